// Round 7
// baseline (89.153 us; speedup 1.0000x reference)
//
#include <hip/hip_runtime.h>

#define RES 1024
#define NV 8
#define HW (RES * RES)

typedef float f32x4 __attribute__((ext_vector_type(4)));

// ---------------------------------------------------------------- bbox partial scan
// 64 blocks per view; each block reduces its 4096-quad chunk into one int4 partial.
__global__ __launch_bounds__(256) void bbox_partial(const float* __restrict__ masks,
                                                    int4* __restrict__ part) {
    const int v = blockIdx.y;
    const int b = blockIdx.x;                 // 0..63
    const float4* m = (const float4*)(masks + (size_t)v * HW);
    int lminy = 1 << 30, lmaxy = -1, lminx = 1 << 30, lmaxx = -1;
    int base = b * 4096 + threadIdx.x;
#pragma unroll 4
    for (int i = 0; i < 16; ++i) {
        int q = base + i * 256;
        float4 f = m[q];
        bool a = f.x > 0.5f, bb = f.y > 0.5f, c = f.z > 0.5f, d = f.w > 0.5f;
        if (a | bb | c | d) {
            int lin = q << 2;
            int y = lin >> 10;
            int x = lin & (RES - 1);
            lminy = min(lminy, y); lmaxy = max(lmaxy, y);
            if (a)  { lminx = min(lminx, x);     lmaxx = max(lmaxx, x);     }
            if (bb) { lminx = min(lminx, x + 1); lmaxx = max(lmaxx, x + 1); }
            if (c)  { lminx = min(lminx, x + 2); lmaxx = max(lmaxx, x + 2); }
            if (d)  { lminx = min(lminx, x + 3); lmaxx = max(lmaxx, x + 3); }
        }
    }
    __shared__ int s[4];
    if (threadIdx.x == 0) { s[0] = 1 << 30; s[1] = -1; s[2] = 1 << 30; s[3] = -1; }
    __syncthreads();
    if (lmaxy >= 0) {
        atomicMin(&s[0], lminy); atomicMax(&s[1], lmaxy);
        atomicMin(&s[2], lminx); atomicMax(&s[3], lmaxx);
    }
    __syncthreads();
    if (threadIdx.x == 0) part[v * 64 + b] = make_int4(s[0], s[1], s[2], s[3]);
}

// ---------------------------------------------------------------- resample + rot90
// Output-tile-indexed: out[i,j] = S[y=j, x=1023-i]. Since both scales <= 1,
// a 32x32 output tile's source footprint is <= 33x33 per plane. Stage the 4
// plane windows in LDS with coalesced row loads; bilinear/nearest from LDS;
// direct float4 NT stores (rot90 is pure indexing — no transpose tile).
__global__ __launch_bounds__(256) void resample_kernel(const float* __restrict__ rgbs,
                                                       const float* __restrict__ masks,
                                                       const int4* __restrict__ part,
                                                       const float* __restrict__ kc,
                                                       float* __restrict__ out,
                                                       float* __restrict__ kc_out) {
    const int v = blockIdx.z;
    const int i0 = blockIdx.x * 32;   // output row tile
    const int j0 = blockIdx.y * 32;   // output col tile
    const int t = threadIdx.x;        // 0..255
    const int il = t >> 3;            // 0..31: output row within tile
    const int jg = t & 7;             // float4 group within row

    __shared__ float Pp[10];

    if (t < 64) {
        int4 p = part[v * 64 + t];
        int bminh = p.x, bmaxh = p.y, bminw = p.z, bmaxw = p.w;
#pragma unroll
        for (int o = 32; o; o >>= 1) {
            bminh = min(bminh, __shfl_down(bminh, o));
            bmaxh = max(bmaxh, __shfl_down(bmaxh, o));
            bminw = min(bminw, __shfl_down(bminw, o));
            bmaxw = max(bmaxw, __shfl_down(bmaxw, o));
        }
        if (t == 0) {
            if (bmaxh < 0) { bminh = 0; bmaxh = RES - 1; }   // empty-mask fallback
            if (bmaxw < 0) { bminw = 0; bmaxw = RES - 1; }
            float mh = (float)min(max(bminh - 100, 0), RES - 1);
            float Mh = (float)min(max(bmaxh + 100, 0), RES - 1);
            float mw = (float)min(max(bminw - 100, 0), RES - 1);
            float Mw = (float)min(max(bmaxw + 100, 0), RES - 1);
            float hn = Mh - mh, wn = Mw - mw;
            bool vert = (hn >= wn);
            float ohf = vert ? 1024.0f : floorf(__fdiv_rn(__fmul_rn(hn, 1024.0f), wn));
            float owf = vert ? floorf(__fdiv_rn(__fmul_rn(wn, 1024.0f), hn)) : 1024.0f;
            float ptp = floorf(__fmul_rn(1024.0f - ohf, 0.5f));
            float plp = floorf(__fmul_rn(1024.0f - owf, 0.5f));
            Pp[0] = mh; Pp[1] = mw; Pp[2] = hn; Pp[3] = wn;
            Pp[4] = ohf; Pp[5] = owf; Pp[6] = ptp; Pp[7] = plp;
            Pp[8] = __fdiv_rn(wn, owf);
            Pp[9] = __fdiv_rn(hn, ohf);
            if (i0 == 0 && j0 == 0) {
                // kc_new = R @ (A @ kc),  R = [[0,1,0],[-1,0,1024],[0,0,1]]
                float axk = __fdiv_rn(owf, wn), ayk = __fdiv_rn(ohf, hn);
                float t0 = plp - mw * axk;
                float t1 = ptp - mh * ayk;
                const float* K = kc + v * 9;
                float* O = kc_out + v * 9;
#pragma unroll
                for (int k = 0; k < 3; ++k) {
                    float M0 = axk * K[k]     + t0 * K[6 + k];
                    float M1 = ayk * K[3 + k] + t1 * K[6 + k];
                    float M2 = K[6 + k];
                    O[k]     = M1;
                    O[3 + k] = -M0 + 1024.0f * M2;
                    O[6 + k] = M2;
                }
            }
        }
    }
    __syncthreads();

    const float mh = Pp[0], mw = Pp[1], hn = Pp[2], wn = Pp[3];
    const float ohf = Pp[4], owf = Pp[5], pt = Pp[6], pl = Pp[7];
    const float sxi = Pp[8], syi = Pp[9];

    float* outp[4];
#pragma unroll
    for (int p = 0; p < 3; ++p) outp[p] = out + (size_t)(v * 3 + p) * HW;
    outp[3] = out + (size_t)(NV * 3) * HW + (size_t)v * HW;
    const size_t obase = (size_t)(i0 + il) * RES + j0 + 4 * jg;

    const int x0b = 992 - i0;   // S x range of this tile: [x0b, x0b+31]

    // tile validity vs valid window [pl, pl+ow) in x, [pt, pt+oh) in y(=j)
    bool anyv = ((float)(x0b + 31) >= pl) && ((float)x0b < pl + owf) &&
                ((float)(j0 + 31) >= pt) && ((float)j0 < pt + ohf);
    if (!anyv) {
        f32x4 z4 = (f32x4)0.0f;
#pragma unroll
        for (int p = 0; p < 4; ++p)
            __builtin_nontemporal_store(z4, (f32x4*)(outp[p] + obase));
        return;
    }

    // --- source window bounds (uniform per block; same FP ops as per-pixel path,
    // monotone in xs/ys, so window covers all per-pixel coords incl. nearest) ---
    float sxl = fmaxf(__fadd_rn(__fmul_rn(__fadd_rn((float)x0b - pl, 0.5f), sxi), -0.5f), 0.0f);
    float sxh = fmaxf(__fadd_rn(__fmul_rn(__fadd_rn((float)(x0b + 31) - pl, 0.5f), sxi), -0.5f), 0.0f);
    int gxlo = (int)(fminf(fmaxf(floorf(sxl), 0.0f), wn - 1.0f) + mw);
    float x0fh = fminf(fmaxf(floorf(sxh), 0.0f), wn - 1.0f);
    int gxhi = (int)(fminf(x0fh + 1.0f, wn - 1.0f) + mw);
    float syl = fmaxf(__fadd_rn(__fmul_rn(__fadd_rn((float)j0 - pt, 0.5f), syi), -0.5f), 0.0f);
    float syh = fmaxf(__fadd_rn(__fmul_rn(__fadd_rn((float)(j0 + 31) - pt, 0.5f), syi), -0.5f), 0.0f);
    int gylo = (int)(fminf(fmaxf(floorf(syl), 0.0f), hn - 1.0f) + mh);
    float y0fh = fminf(fmaxf(floorf(syh), 0.0f), hn - 1.0f);
    int gyhi = (int)(fminf(y0fh + 1.0f, hn - 1.0f) + mh);
    const int W = gxhi - gxlo + 1;   // <= 33
    const int H = gyhi - gylo + 1;   // <= 33

    __shared__ float sbuf[4][33 * 37];
    {
        const float* srcs[4] = { rgbs + (size_t)(v * 3 + 0) * HW,
                                 rgbs + (size_t)(v * 3 + 1) * HW,
                                 rgbs + (size_t)(v * 3 + 2) * HW,
                                 masks + (size_t)v * HW };
        const int rr = t >> 5, cc = t & 31;
#pragma unroll
        for (int p = 0; p < 4; ++p) {
            const float* s = srcs[p] + (size_t)gylo * RES + gxlo;
            for (int r = rr; r < H; r += 8)
                for (int c = cc; c < W; c += 32)
                    sbuf[p][r * 37 + c] = s[r * RES + c];
        }
    }
    __syncthreads();

    // --- per-thread x coords (single: x = x0b + 31 - il) ---
    float xs = (float)(x0b + 31 - il) - pl;
    bool vx = (xs >= 0.0f) && (xs < owf);
    float sx = fmaxf(__fadd_rn(__fmul_rn(__fadd_rn(xs, 0.5f), sxi), -0.5f), 0.0f);
    float flx = floorf(sx);
    float fx = sx - flx;
    float x0f = fminf(fmaxf(flx, 0.0f), wn - 1.0f);
    float x1f = fminf(x0f + 1.0f, wn - 1.0f);
    const int lx0 = (int)(x0f + mw) - gxlo;
    const int lx1 = (int)(x1f + mw) - gxlo;
    const int lnx = (int)(fminf(fmaxf(floorf(__fmul_rn(xs, sxi)), 0.0f), wn - 1.0f) + mw) - gxlo;
    const float omfx = 1.0f - fx;

    // --- per-thread y coords, 4 consecutive j ---
    int b0[4], b1[4], bn[4];
    float fy[4];
    bool vv[4];
#pragma unroll
    for (int jj = 0; jj < 4; ++jj) {
        float ys = (float)(j0 + 4 * jg + jj) - pt;
        vv[jj] = vx & (ys >= 0.0f) & (ys < ohf);
        float sy = fmaxf(__fadd_rn(__fmul_rn(__fadd_rn(ys, 0.5f), syi), -0.5f), 0.0f);
        float fly = floorf(sy);
        fy[jj] = sy - fly;
        float y0f = fminf(fmaxf(fly, 0.0f), hn - 1.0f);
        float y1f = fminf(y0f + 1.0f, hn - 1.0f);
        b0[jj] = ((int)(y0f + mh) - gylo) * 37;
        b1[jj] = ((int)(y1f + mh) - gylo) * 37;
        bn[jj] = ((int)(fminf(fmaxf(floorf(__fmul_rn(ys, syi)), 0.0f), hn - 1.0f) + mh) - gylo) * 37;
    }

#pragma unroll
    for (int p = 0; p < 3; ++p) {
        f32x4 w;
#pragma unroll
        for (int jj = 0; jj < 4; ++jj) {
            float val = 0.0f;
            if (vv[jj]) {
                float a = sbuf[p][b0[jj] + lx0];
                float b = sbuf[p][b0[jj] + lx1];
                float c = sbuf[p][b1[jj] + lx0];
                float d = sbuf[p][b1[jj] + lx1];
                float top = a * omfx + b * fx;
                float bot = c * omfx + d * fx;
                val = top * (1.0f - fy[jj]) + bot * fy[jj];
            }
            w[jj] = val;
        }
        __builtin_nontemporal_store(w, (f32x4*)(outp[p] + obase));
    }
    {
        f32x4 w;
#pragma unroll
        for (int jj = 0; jj < 4; ++jj)
            w[jj] = vv[jj] ? sbuf[3][bn[jj] + lnx] : 0.0f;
        __builtin_nontemporal_store(w, (f32x4*)(outp[3] + obase));
    }
}

extern "C" void kernel_launch(void* const* d_in, const int* in_sizes, int n_in,
                              void* d_out, int out_size, void* d_ws, size_t ws_size,
                              hipStream_t stream) {
    const float* rgbs  = (const float*)d_in[0];
    const float* masks = (const float*)d_in[1];
    const float* kc    = (const float*)d_in[2];
    float* out = (float*)d_out;
    int4* part = (int4*)d_ws;                              // NV*64*16 = 8192 B
    float* kc_out = out + (size_t)NV * 3 * HW + (size_t)NV * HW;   // offset 33554432

    bbox_partial<<<dim3(64, NV), 256, 0, stream>>>(masks, part);
    resample_kernel<<<dim3(32, 32, NV), 256, 0, stream>>>(
        rgbs, masks, part, kc, out, kc_out);
}

// Round 8
// 71.983 us; speedup vs baseline: 1.2385x; 1.2385x over previous
//
#include <hip/hip_runtime.h>

#define RES 1024
#define NV 8
#define HW (RES * RES)

typedef float f32x4 __attribute__((ext_vector_type(4)));
typedef float f32x2 __attribute__((ext_vector_type(2)));

// ---------------------------------------------------------------- bbox partial scan
// 128 blocks per view; each block reduces its 2048-quad chunk into one int4 partial.
__global__ __launch_bounds__(256) void bbox_partial(const float* __restrict__ masks,
                                                    int4* __restrict__ part) {
    const int v = blockIdx.y;
    const int b = blockIdx.x;                 // 0..127
    const float4* m = (const float4*)(masks + (size_t)v * HW);
    int lminy = 1 << 30, lmaxy = -1, lminx = 1 << 30, lmaxx = -1;
    int base = b * 2048 + threadIdx.x;
#pragma unroll
    for (int i = 0; i < 8; ++i) {
        int q = base + i * 256;
        float4 f = m[q];
        bool a = f.x > 0.5f, bb = f.y > 0.5f, c = f.z > 0.5f, d = f.w > 0.5f;
        if (a | bb | c | d) {
            int lin = q << 2;
            int y = lin >> 10;
            int x = lin & (RES - 1);
            lminy = min(lminy, y); lmaxy = max(lmaxy, y);
            if (a)  { lminx = min(lminx, x);     lmaxx = max(lmaxx, x);     }
            if (bb) { lminx = min(lminx, x + 1); lmaxx = max(lmaxx, x + 1); }
            if (c)  { lminx = min(lminx, x + 2); lmaxx = max(lmaxx, x + 2); }
            if (d)  { lminx = min(lminx, x + 3); lmaxx = max(lmaxx, x + 3); }
        }
    }
    __shared__ int s[4];
    if (threadIdx.x == 0) { s[0] = 1 << 30; s[1] = -1; s[2] = 1 << 30; s[3] = -1; }
    __syncthreads();
    if (lmaxy >= 0) {
        atomicMin(&s[0], lminy); atomicMax(&s[1], lmaxy);
        atomicMin(&s[2], lminx); atomicMax(&s[3], lmaxx);
    }
    __syncthreads();
    if (threadIdx.x == 0) part[v * 128 + b] = make_int4(s[0], s[1], s[2], s[3]);
}

// ---------------------------------------------------------------- resample + rot90 (+params prologue)
// Prologue: wave 0 reduces the view's 128 bbox partials, lane 0 computes params
// into LDS (block (0,0) also writes kc_new). Then: pre-rotation sample S[v,c,y,x];
// output out[i,j] = S[j, RES-1-i]; 4 plane tiles in LDS; float4 NT stores.
// Bilinear corner pairs loaded as ONE 8-byte dwordx2 (4B-aligned legal on CDNA).
__global__ __launch_bounds__(256) void resample_kernel(const float* __restrict__ rgbs,
                                                       const float* __restrict__ masks,
                                                       const int4* __restrict__ part,
                                                       const float* __restrict__ kc,
                                                       float* __restrict__ out,
                                                       float* __restrict__ kc_out) {
    const int v = blockIdx.z;
    const int x0b = blockIdx.x * 32;
    const int y0b = blockIdx.y * 32;
    const int t = threadIdx.x;        // 0..255
    const int tx = t & 31;            // x within S tile
    const int ty = t >> 5;            // 0..7
    const int il = t >> 3;            // output row within tile (epilogue)
    const int q  = t & 7;             // float4 group (epilogue)
    const int ibase = 992 - x0b;      // RES-1-(x0b+31)

    __shared__ float Pp[10];

    if (t < 64) {
        int4 pa = part[v * 128 + t];
        int4 pb = part[v * 128 + 64 + t];
        int bminh = min(pa.x, pb.x), bmaxh = max(pa.y, pb.y);
        int bminw = min(pa.z, pb.z), bmaxw = max(pa.w, pb.w);
#pragma unroll
        for (int o = 32; o; o >>= 1) {
            bminh = min(bminh, __shfl_down(bminh, o));
            bmaxh = max(bmaxh, __shfl_down(bmaxh, o));
            bminw = min(bminw, __shfl_down(bminw, o));
            bmaxw = max(bmaxw, __shfl_down(bmaxw, o));
        }
        if (t == 0) {
            if (bmaxh < 0) { bminh = 0; bmaxh = RES - 1; }   // empty-mask fallback
            if (bmaxw < 0) { bminw = 0; bmaxw = RES - 1; }
            float mh = (float)min(max(bminh - 100, 0), RES - 1);
            float Mh = (float)min(max(bmaxh + 100, 0), RES - 1);
            float mw = (float)min(max(bminw - 100, 0), RES - 1);
            float Mw = (float)min(max(bmaxw + 100, 0), RES - 1);
            float hn = Mh - mh, wn = Mw - mw;
            bool vert = (hn >= wn);
            float ohf = vert ? 1024.0f : floorf(__fdiv_rn(__fmul_rn(hn, 1024.0f), wn));
            float owf = vert ? floorf(__fdiv_rn(__fmul_rn(wn, 1024.0f), hn)) : 1024.0f;
            float ptp = floorf(__fmul_rn(1024.0f - ohf, 0.5f));
            float plp = floorf(__fmul_rn(1024.0f - owf, 0.5f));
            Pp[0] = mh; Pp[1] = mw; Pp[2] = hn; Pp[3] = wn;
            Pp[4] = ohf; Pp[5] = owf; Pp[6] = ptp; Pp[7] = plp;
            Pp[8] = __fdiv_rn(wn, owf);
            Pp[9] = __fdiv_rn(hn, ohf);
            if (x0b == 0 && y0b == 0) {
                // kc_new = R @ (A @ kc),  R = [[0,1,0],[-1,0,1024],[0,0,1]] (ROT_DEG==1)
                float axk = __fdiv_rn(owf, wn), ayk = __fdiv_rn(ohf, hn);
                float t0 = plp - mw * axk;
                float t1 = ptp - mh * ayk;
                const float* K = kc + v * 9;
                float* O = kc_out + v * 9;
#pragma unroll
                for (int k = 0; k < 3; ++k) {
                    float M0 = axk * K[k]     + t0 * K[6 + k];
                    float M1 = ayk * K[3 + k] + t1 * K[6 + k];
                    float M2 = K[6 + k];
                    O[k]     = M1;
                    O[3 + k] = -M0 + 1024.0f * M2;
                    O[6 + k] = M2;
                }
            }
        }
    }
    __syncthreads();

    const float mh = Pp[0], mw = Pp[1], hn = Pp[2], wn = Pp[3];
    const float ohf = Pp[4], owf = Pp[5], pt = Pp[6], pl = Pp[7];
    const float sxi = Pp[8], syi = Pp[9];

    float* outp[4];
#pragma unroll
    for (int p = 0; p < 3; ++p) outp[p] = out + (size_t)(v * 3 + p) * HW;
    outp[3] = out + (size_t)(NV * 3) * HW + (size_t)v * HW;
    const size_t obase = (size_t)(ibase + il) * RES + y0b + 4 * q;

    // tile-level validity vs valid window [pl, pl+ow) x [pt, pt+oh)
    bool anyv = ((float)(x0b + 31) >= pl) && ((float)x0b < pl + owf) &&
                ((float)(y0b + 31) >= pt) && ((float)y0b < pt + ohf);
    if (!anyv) {
        f32x4 z4 = (f32x4)0.0f;
#pragma unroll
        for (int p = 0; p < 4; ++p)
            __builtin_nontemporal_store(z4, (f32x4*)(outp[p] + obase));
        return;
    }

    // per-thread x (S column) coords
    float xs = (float)(x0b + tx) - pl;
    bool vx = (xs >= 0.0f) && (xs < owf);
    float sx = fmaxf(__fadd_rn(__fmul_rn(__fadd_rn(xs, 0.5f), sxi), -0.5f), 0.0f);
    float flx = floorf(sx);
    float fx = sx - flx;
    float x0f = fminf(fmaxf(flx, 0.0f), wn - 1.0f);
    float x1f = fminf(x0f + 1.0f, wn - 1.0f);
    int gx0 = (int)(x0f + mw);
    int gx1 = (int)(x1f + mw);
    float nxf = fminf(fmaxf(floorf(__fmul_rn(xs, sxi)), 0.0f), wn - 1.0f);
    int gnx = (int)(nxf + mw);

    // paired-load offsets: corners (gx0, gx1) sit in one 8B window at off
    const int off  = min(gx0, RES - 2);
    const int ia   = gx0 - off;            // 0 or 1
    const int ib   = gx1 - off;            // 0 or 1 (gx1 <= off+1 always)

    // per-thread y (S row) coords, 4 sub-rows
    int gy0[4], gy1[4], gny[4];
    float fy[4];
    bool vyk[4];
#pragma unroll
    for (int k = 0; k < 4; ++k) {
        float ysf = (float)(y0b + ty + 8 * k) - pt;
        vyk[k] = (ysf >= 0.0f) && (ysf < ohf);
        float sy = fmaxf(__fadd_rn(__fmul_rn(__fadd_rn(ysf, 0.5f), syi), -0.5f), 0.0f);
        float fly = floorf(sy);
        fy[k] = sy - fly;
        float y0f = fminf(fmaxf(fly, 0.0f), hn - 1.0f);
        float y1f = fminf(y0f + 1.0f, hn - 1.0f);
        gy0[k] = (int)(y0f + mh);
        gy1[k] = (int)(y1f + mh);
        float nyf = fminf(fmaxf(floorf(__fmul_rn(ysf, syi)), 0.0f), hn - 1.0f);
        gny[k] = (int)(nyf + mh);
    }

    __shared__ float tile[4][32][33];   // [plane][y_local][x_local]

#pragma unroll
    for (int p = 0; p < 3; ++p) {
        const float* img = rgbs + (size_t)(v * 3 + p) * HW;
        float omfx = 1.0f - fx;
#pragma unroll
        for (int k = 0; k < 4; ++k) {
            float val = 0.0f;
            if (vx & vyk[k]) {
                f32x2 p0, p1;
                __builtin_memcpy(&p0, img + gy0[k] * RES + off, 8);
                __builtin_memcpy(&p1, img + gy1[k] * RES + off, 8);
                float a = ia ? p0.y : p0.x;
                float b = ib ? p0.y : p0.x;
                float c = ia ? p1.y : p1.x;
                float d = ib ? p1.y : p1.x;
                float top = a * omfx + b * fx;
                float bot = c * omfx + d * fx;
                val = top * (1.0f - fy[k]) + bot * fy[k];
            }
            tile[p][ty + 8 * k][tx] = val;
        }
    }
    {
        const float* img = masks + (size_t)v * HW;
#pragma unroll
        for (int k = 0; k < 4; ++k)
            tile[3][ty + 8 * k][tx] = (vx & vyk[k]) ? img[gny[k] * RES + gnx] : 0.0f;
    }

    __syncthreads();

    const int xl = 31 - il;   // S x_local for this output row
#pragma unroll
    for (int p = 0; p < 4; ++p) {
        f32x4 w;
        w.x = tile[p][4 * q + 0][xl];
        w.y = tile[p][4 * q + 1][xl];
        w.z = tile[p][4 * q + 2][xl];
        w.w = tile[p][4 * q + 3][xl];
        __builtin_nontemporal_store(w, (f32x4*)(outp[p] + obase));
    }
}

extern "C" void kernel_launch(void* const* d_in, const int* in_sizes, int n_in,
                              void* d_out, int out_size, void* d_ws, size_t ws_size,
                              hipStream_t stream) {
    const float* rgbs  = (const float*)d_in[0];
    const float* masks = (const float*)d_in[1];
    const float* kc    = (const float*)d_in[2];
    float* out = (float*)d_out;
    int4* part = (int4*)d_ws;                              // NV*128*16 = 16384 B
    float* kc_out = out + (size_t)NV * 3 * HW + (size_t)NV * HW;   // offset 33554432

    bbox_partial<<<dim3(128, NV), 256, 0, stream>>>(masks, part);
    resample_kernel<<<dim3(RES / 32, RES / 32, NV), 256, 0, stream>>>(
        rgbs, masks, part, kc, out, kc_out);
}

// Round 9
// 69.546 us; speedup vs baseline: 1.2819x; 1.0350x over previous
//
#include <hip/hip_runtime.h>

#define RES 1024
#define NV 8
#define HW (RES * RES)

typedef float f32x4 __attribute__((ext_vector_type(4)));
typedef float f32x2 __attribute__((ext_vector_type(2)));

// ---------------------------------------------------------------- bbox partial scan
// 128 blocks per view; each block reduces its 2048-quad chunk into one int4 partial.
__global__ __launch_bounds__(256) void bbox_partial(const float* __restrict__ masks,
                                                    int4* __restrict__ part) {
    const int v = blockIdx.y;
    const int b = blockIdx.x;                 // 0..127
    const float4* m = (const float4*)(masks + (size_t)v * HW);
    int lminy = 1 << 30, lmaxy = -1, lminx = 1 << 30, lmaxx = -1;
    int base = b * 2048 + threadIdx.x;
#pragma unroll
    for (int i = 0; i < 8; ++i) {
        int q = base + i * 256;
        float4 f = m[q];
        bool a = f.x > 0.5f, bb = f.y > 0.5f, c = f.z > 0.5f, d = f.w > 0.5f;
        if (a | bb | c | d) {
            int lin = q << 2;
            int y = lin >> 10;
            int x = lin & (RES - 1);
            lminy = min(lminy, y); lmaxy = max(lmaxy, y);
            if (a)  { lminx = min(lminx, x);     lmaxx = max(lmaxx, x);     }
            if (bb) { lminx = min(lminx, x + 1); lmaxx = max(lmaxx, x + 1); }
            if (c)  { lminx = min(lminx, x + 2); lmaxx = max(lmaxx, x + 2); }
            if (d)  { lminx = min(lminx, x + 3); lmaxx = max(lmaxx, x + 3); }
        }
    }
    __shared__ int s[4];
    if (threadIdx.x == 0) { s[0] = 1 << 30; s[1] = -1; s[2] = 1 << 30; s[3] = -1; }
    __syncthreads();
    if (lmaxy >= 0) {
        atomicMin(&s[0], lminy); atomicMax(&s[1], lmaxy);
        atomicMin(&s[2], lminx); atomicMax(&s[3], lmaxx);
    }
    __syncthreads();
    if (threadIdx.x == 0) part[v * 128 + b] = make_int4(s[0], s[1], s[2], s[3]);
}

// ---------------------------------------------------------------- resample + rot90 (+params prologue)
// ALL 28 gathers issued up-front into registers (one vmcnt drain per thread,
// not one per plane); validity applied as a final select (loads are always
// in-bounds since coords are pre-clamped). Then LDS transpose + float4 NT stores.
__global__ __launch_bounds__(256) void resample_kernel(const float* __restrict__ rgbs,
                                                       const float* __restrict__ masks,
                                                       const int4* __restrict__ part,
                                                       const float* __restrict__ kc,
                                                       float* __restrict__ out,
                                                       float* __restrict__ kc_out) {
    const int v = blockIdx.z;
    const int x0b = blockIdx.x * 32;
    const int y0b = blockIdx.y * 32;
    const int t = threadIdx.x;        // 0..255
    const int tx = t & 31;            // x within S tile
    const int ty = t >> 5;            // 0..7
    const int il = t >> 3;            // output row within tile (epilogue)
    const int q  = t & 7;             // float4 group (epilogue)
    const int ibase = 992 - x0b;      // RES-1-(x0b+31)

    __shared__ float Pp[10];

    if (t < 64) {
        int4 pa = part[v * 128 + t];
        int4 pb = part[v * 128 + 64 + t];
        int bminh = min(pa.x, pb.x), bmaxh = max(pa.y, pb.y);
        int bminw = min(pa.z, pb.z), bmaxw = max(pa.w, pb.w);
#pragma unroll
        for (int o = 32; o; o >>= 1) {
            bminh = min(bminh, __shfl_down(bminh, o));
            bmaxh = max(bmaxh, __shfl_down(bmaxh, o));
            bminw = min(bminw, __shfl_down(bminw, o));
            bmaxw = max(bmaxw, __shfl_down(bmaxw, o));
        }
        if (t == 0) {
            if (bmaxh < 0) { bminh = 0; bmaxh = RES - 1; }   // empty-mask fallback
            if (bmaxw < 0) { bminw = 0; bmaxw = RES - 1; }
            float mh = (float)min(max(bminh - 100, 0), RES - 1);
            float Mh = (float)min(max(bmaxh + 100, 0), RES - 1);
            float mw = (float)min(max(bminw - 100, 0), RES - 1);
            float Mw = (float)min(max(bmaxw + 100, 0), RES - 1);
            float hn = Mh - mh, wn = Mw - mw;
            bool vert = (hn >= wn);
            float ohf = vert ? 1024.0f : floorf(__fdiv_rn(__fmul_rn(hn, 1024.0f), wn));
            float owf = vert ? floorf(__fdiv_rn(__fmul_rn(wn, 1024.0f), hn)) : 1024.0f;
            float ptp = floorf(__fmul_rn(1024.0f - ohf, 0.5f));
            float plp = floorf(__fmul_rn(1024.0f - owf, 0.5f));
            Pp[0] = mh; Pp[1] = mw; Pp[2] = hn; Pp[3] = wn;
            Pp[4] = ohf; Pp[5] = owf; Pp[6] = ptp; Pp[7] = plp;
            Pp[8] = __fdiv_rn(wn, owf);
            Pp[9] = __fdiv_rn(hn, ohf);
            if (x0b == 0 && y0b == 0) {
                // kc_new = R @ (A @ kc),  R = [[0,1,0],[-1,0,1024],[0,0,1]] (ROT_DEG==1)
                float axk = __fdiv_rn(owf, wn), ayk = __fdiv_rn(ohf, hn);
                float t0 = plp - mw * axk;
                float t1 = ptp - mh * ayk;
                const float* K = kc + v * 9;
                float* O = kc_out + v * 9;
#pragma unroll
                for (int k = 0; k < 3; ++k) {
                    float M0 = axk * K[k]     + t0 * K[6 + k];
                    float M1 = ayk * K[3 + k] + t1 * K[6 + k];
                    float M2 = K[6 + k];
                    O[k]     = M1;
                    O[3 + k] = -M0 + 1024.0f * M2;
                    O[6 + k] = M2;
                }
            }
        }
    }
    __syncthreads();

    const float mh = Pp[0], mw = Pp[1], hn = Pp[2], wn = Pp[3];
    const float ohf = Pp[4], owf = Pp[5], pt = Pp[6], pl = Pp[7];
    const float sxi = Pp[8], syi = Pp[9];

    float* outp[4];
#pragma unroll
    for (int p = 0; p < 3; ++p) outp[p] = out + (size_t)(v * 3 + p) * HW;
    outp[3] = out + (size_t)(NV * 3) * HW + (size_t)v * HW;
    const size_t obase = (size_t)(ibase + il) * RES + y0b + 4 * q;

    // tile-level validity vs valid window [pl, pl+ow) x [pt, pt+oh)
    bool anyv = ((float)(x0b + 31) >= pl) && ((float)x0b < pl + owf) &&
                ((float)(y0b + 31) >= pt) && ((float)y0b < pt + ohf);
    if (!anyv) {
        f32x4 z4 = (f32x4)0.0f;
#pragma unroll
        for (int p = 0; p < 4; ++p)
            __builtin_nontemporal_store(z4, (f32x4*)(outp[p] + obase));
        return;
    }

    // per-thread x (S column) coords
    float xs = (float)(x0b + tx) - pl;
    bool vx = (xs >= 0.0f) && (xs < owf);
    float sx = fmaxf(__fadd_rn(__fmul_rn(__fadd_rn(xs, 0.5f), sxi), -0.5f), 0.0f);
    float flx = floorf(sx);
    float fx = sx - flx;
    float x0f = fminf(fmaxf(flx, 0.0f), wn - 1.0f);
    float x1f = fminf(x0f + 1.0f, wn - 1.0f);
    int gx0 = (int)(x0f + mw);
    int gx1 = (int)(x1f + mw);
    float nxf = fminf(fmaxf(floorf(__fmul_rn(xs, sxi)), 0.0f), wn - 1.0f);
    int gnx = (int)(nxf + mw);

    // paired-load offsets: corners (gx0, gx1) sit in one 8B window at off
    const int off  = min(gx0, RES - 2);
    const int ia   = gx0 - off;            // 0 or 1
    const int ib   = gx1 - off;            // 0 or 1

    // per-thread y (S row) coords, 4 sub-rows
    int ro0[4], ro1[4], ron[4];
    float fy[4];
    bool vyk[4];
#pragma unroll
    for (int k = 0; k < 4; ++k) {
        float ysf = (float)(y0b + ty + 8 * k) - pt;
        vyk[k] = vx & (ysf >= 0.0f) & (ysf < ohf);
        float sy = fmaxf(__fadd_rn(__fmul_rn(__fadd_rn(ysf, 0.5f), syi), -0.5f), 0.0f);
        float fly = floorf(sy);
        fy[k] = sy - fly;
        float y0f = fminf(fmaxf(fly, 0.0f), hn - 1.0f);
        float y1f = fminf(y0f + 1.0f, hn - 1.0f);
        ro0[k] = ((int)(y0f + mh)) * RES + off;
        ro1[k] = ((int)(y1f + mh)) * RES + off;
        float nyf = fminf(fmaxf(floorf(__fmul_rn(ysf, syi)), 0.0f), hn - 1.0f);
        ron[k] = ((int)(nyf + mh)) * RES + gnx;
    }

    // ---- issue ALL 28 loads up-front (addresses are always in-bounds) ----
    f32x2 P0[3][4], P1[3][4];
    float M[4];
#pragma unroll
    for (int p = 0; p < 3; ++p) {
        const float* img = rgbs + (size_t)(v * 3 + p) * HW;
#pragma unroll
        for (int k = 0; k < 4; ++k) {
            __builtin_memcpy(&P0[p][k], img + ro0[k], 8);
            __builtin_memcpy(&P1[p][k], img + ro1[k], 8);
        }
    }
    {
        const float* img = masks + (size_t)v * HW;
#pragma unroll
        for (int k = 0; k < 4; ++k) M[k] = img[ron[k]];
    }

    __shared__ float tile[4][32][33];   // [plane][y_local][x_local]
    const float omfx = 1.0f - fx;

#pragma unroll
    for (int p = 0; p < 3; ++p) {
#pragma unroll
        for (int k = 0; k < 4; ++k) {
            float a = ia ? P0[p][k].y : P0[p][k].x;
            float b = ib ? P0[p][k].y : P0[p][k].x;
            float c = ia ? P1[p][k].y : P1[p][k].x;
            float d = ib ? P1[p][k].y : P1[p][k].x;
            float top = a * omfx + b * fx;
            float bot = c * omfx + d * fx;
            float val = top * (1.0f - fy[k]) + bot * fy[k];
            tile[p][ty + 8 * k][tx] = vyk[k] ? val : 0.0f;
        }
    }
#pragma unroll
    for (int k = 0; k < 4; ++k)
        tile[3][ty + 8 * k][tx] = vyk[k] ? M[k] : 0.0f;

    __syncthreads();

    const int xl = 31 - il;   // S x_local for this output row
#pragma unroll
    for (int p = 0; p < 4; ++p) {
        f32x4 w;
        w.x = tile[p][4 * q + 0][xl];
        w.y = tile[p][4 * q + 1][xl];
        w.z = tile[p][4 * q + 2][xl];
        w.w = tile[p][4 * q + 3][xl];
        __builtin_nontemporal_store(w, (f32x4*)(outp[p] + obase));
    }
}

extern "C" void kernel_launch(void* const* d_in, const int* in_sizes, int n_in,
                              void* d_out, int out_size, void* d_ws, size_t ws_size,
                              hipStream_t stream) {
    const float* rgbs  = (const float*)d_in[0];
    const float* masks = (const float*)d_in[1];
    const float* kc    = (const float*)d_in[2];
    float* out = (float*)d_out;
    int4* part = (int4*)d_ws;                              // NV*128*16 = 16384 B
    float* kc_out = out + (size_t)NV * 3 * HW + (size_t)NV * HW;   // offset 33554432

    bbox_partial<<<dim3(128, NV), 256, 0, stream>>>(masks, part);
    resample_kernel<<<dim3(RES / 32, RES / 32, NV), 256, 0, stream>>>(
        rgbs, masks, part, kc, out, kc_out);
}

// Round 10
// 69.420 us; speedup vs baseline: 1.2843x; 1.0018x over previous
//
#include <hip/hip_runtime.h>

#define RES 1024
#define NV 8
#define HW (RES * RES)

typedef float f32x4 __attribute__((ext_vector_type(4)));
typedef float f32x2 __attribute__((ext_vector_type(2)));

// ---------------------------------------------------------------- bbox partial scan
// 128 blocks per view; each block reduces its 2048-quad chunk into one int4 partial.
__global__ __launch_bounds__(256) void bbox_partial(const float* __restrict__ masks,
                                                    int4* __restrict__ part) {
    const int v = blockIdx.y;
    const int b = blockIdx.x;                 // 0..127
    const float4* m = (const float4*)(masks + (size_t)v * HW);
    int lminy = 1 << 30, lmaxy = -1, lminx = 1 << 30, lmaxx = -1;
    int base = b * 2048 + threadIdx.x;
#pragma unroll
    for (int i = 0; i < 8; ++i) {
        int q = base + i * 256;
        float4 f = m[q];
        bool a = f.x > 0.5f, bb = f.y > 0.5f, c = f.z > 0.5f, d = f.w > 0.5f;
        if (a | bb | c | d) {
            int lin = q << 2;
            int y = lin >> 10;
            int x = lin & (RES - 1);
            lminy = min(lminy, y); lmaxy = max(lmaxy, y);
            if (a)  { lminx = min(lminx, x);     lmaxx = max(lmaxx, x);     }
            if (bb) { lminx = min(lminx, x + 1); lmaxx = max(lmaxx, x + 1); }
            if (c)  { lminx = min(lminx, x + 2); lmaxx = max(lmaxx, x + 2); }
            if (d)  { lminx = min(lminx, x + 3); lmaxx = max(lmaxx, x + 3); }
        }
    }
    __shared__ int s[4];
    if (threadIdx.x == 0) { s[0] = 1 << 30; s[1] = -1; s[2] = 1 << 30; s[3] = -1; }
    __syncthreads();
    if (lmaxy >= 0) {
        atomicMin(&s[0], lminy); atomicMax(&s[1], lmaxy);
        atomicMin(&s[2], lminx); atomicMax(&s[3], lmaxx);
    }
    __syncthreads();
    if (threadIdx.x == 0) part[v * 128 + b] = make_int4(s[0], s[1], s[2], s[3]);
}

// ---------------------------------------------------------------- resample + rot90 (+params prologue)
// ALL 28 gathers issued up-front into registers; LDS transpose; PLAIN float4
// stores (A/B vs round-9's nontemporal stores — suspected 2-3 TB/s NT cap).
__global__ __launch_bounds__(256) void resample_kernel(const float* __restrict__ rgbs,
                                                       const float* __restrict__ masks,
                                                       const int4* __restrict__ part,
                                                       const float* __restrict__ kc,
                                                       float* __restrict__ out,
                                                       float* __restrict__ kc_out) {
    const int v = blockIdx.z;
    const int x0b = blockIdx.x * 32;
    const int y0b = blockIdx.y * 32;
    const int t = threadIdx.x;        // 0..255
    const int tx = t & 31;            // x within S tile
    const int ty = t >> 5;            // 0..7
    const int il = t >> 3;            // output row within tile (epilogue)
    const int q  = t & 7;             // float4 group (epilogue)
    const int ibase = 992 - x0b;      // RES-1-(x0b+31)

    __shared__ float Pp[10];

    if (t < 64) {
        int4 pa = part[v * 128 + t];
        int4 pb = part[v * 128 + 64 + t];
        int bminh = min(pa.x, pb.x), bmaxh = max(pa.y, pb.y);
        int bminw = min(pa.z, pb.z), bmaxw = max(pa.w, pb.w);
#pragma unroll
        for (int o = 32; o; o >>= 1) {
            bminh = min(bminh, __shfl_down(bminh, o));
            bmaxh = max(bmaxh, __shfl_down(bmaxh, o));
            bminw = min(bminw, __shfl_down(bminw, o));
            bmaxw = max(bmaxw, __shfl_down(bmaxw, o));
        }
        if (t == 0) {
            if (bmaxh < 0) { bminh = 0; bmaxh = RES - 1; }   // empty-mask fallback
            if (bmaxw < 0) { bminw = 0; bmaxw = RES - 1; }
            float mh = (float)min(max(bminh - 100, 0), RES - 1);
            float Mh = (float)min(max(bmaxh + 100, 0), RES - 1);
            float mw = (float)min(max(bminw - 100, 0), RES - 1);
            float Mw = (float)min(max(bmaxw + 100, 0), RES - 1);
            float hn = Mh - mh, wn = Mw - mw;
            bool vert = (hn >= wn);
            float ohf = vert ? 1024.0f : floorf(__fdiv_rn(__fmul_rn(hn, 1024.0f), wn));
            float owf = vert ? floorf(__fdiv_rn(__fmul_rn(wn, 1024.0f), hn)) : 1024.0f;
            float ptp = floorf(__fmul_rn(1024.0f - ohf, 0.5f));
            float plp = floorf(__fmul_rn(1024.0f - owf, 0.5f));
            Pp[0] = mh; Pp[1] = mw; Pp[2] = hn; Pp[3] = wn;
            Pp[4] = ohf; Pp[5] = owf; Pp[6] = ptp; Pp[7] = plp;
            Pp[8] = __fdiv_rn(wn, owf);
            Pp[9] = __fdiv_rn(hn, ohf);
            if (x0b == 0 && y0b == 0) {
                // kc_new = R @ (A @ kc),  R = [[0,1,0],[-1,0,1024],[0,0,1]] (ROT_DEG==1)
                float axk = __fdiv_rn(owf, wn), ayk = __fdiv_rn(ohf, hn);
                float t0 = plp - mw * axk;
                float t1 = ptp - mh * ayk;
                const float* K = kc + v * 9;
                float* O = kc_out + v * 9;
#pragma unroll
                for (int k = 0; k < 3; ++k) {
                    float M0 = axk * K[k]     + t0 * K[6 + k];
                    float M1 = ayk * K[3 + k] + t1 * K[6 + k];
                    float M2 = K[6 + k];
                    O[k]     = M1;
                    O[3 + k] = -M0 + 1024.0f * M2;
                    O[6 + k] = M2;
                }
            }
        }
    }
    __syncthreads();

    const float mh = Pp[0], mw = Pp[1], hn = Pp[2], wn = Pp[3];
    const float ohf = Pp[4], owf = Pp[5], pt = Pp[6], pl = Pp[7];
    const float sxi = Pp[8], syi = Pp[9];

    float* outp[4];
#pragma unroll
    for (int p = 0; p < 3; ++p) outp[p] = out + (size_t)(v * 3 + p) * HW;
    outp[3] = out + (size_t)(NV * 3) * HW + (size_t)v * HW;
    const size_t obase = (size_t)(ibase + il) * RES + y0b + 4 * q;

    // tile-level validity vs valid window [pl, pl+ow) x [pt, pt+oh)
    bool anyv = ((float)(x0b + 31) >= pl) && ((float)x0b < pl + owf) &&
                ((float)(y0b + 31) >= pt) && ((float)y0b < pt + ohf);
    if (!anyv) {
        f32x4 z4 = (f32x4)0.0f;
#pragma unroll
        for (int p = 0; p < 4; ++p)
            *(f32x4*)(outp[p] + obase) = z4;
        return;
    }

    // per-thread x (S column) coords
    float xs = (float)(x0b + tx) - pl;
    bool vx = (xs >= 0.0f) && (xs < owf);
    float sx = fmaxf(__fadd_rn(__fmul_rn(__fadd_rn(xs, 0.5f), sxi), -0.5f), 0.0f);
    float flx = floorf(sx);
    float fx = sx - flx;
    float x0f = fminf(fmaxf(flx, 0.0f), wn - 1.0f);
    float x1f = fminf(x0f + 1.0f, wn - 1.0f);
    int gx0 = (int)(x0f + mw);
    int gx1 = (int)(x1f + mw);
    float nxf = fminf(fmaxf(floorf(__fmul_rn(xs, sxi)), 0.0f), wn - 1.0f);
    int gnx = (int)(nxf + mw);

    // paired-load offsets: corners (gx0, gx1) sit in one 8B window at off
    const int off  = min(gx0, RES - 2);
    const int ia   = gx0 - off;            // 0 or 1
    const int ib   = gx1 - off;            // 0 or 1

    // per-thread y (S row) coords, 4 sub-rows
    int ro0[4], ro1[4], ron[4];
    float fy[4];
    bool vyk[4];
#pragma unroll
    for (int k = 0; k < 4; ++k) {
        float ysf = (float)(y0b + ty + 8 * k) - pt;
        vyk[k] = vx & (ysf >= 0.0f) & (ysf < ohf);
        float sy = fmaxf(__fadd_rn(__fmul_rn(__fadd_rn(ysf, 0.5f), syi), -0.5f), 0.0f);
        float fly = floorf(sy);
        fy[k] = sy - fly;
        float y0f = fminf(fmaxf(fly, 0.0f), hn - 1.0f);
        float y1f = fminf(y0f + 1.0f, hn - 1.0f);
        ro0[k] = ((int)(y0f + mh)) * RES + off;
        ro1[k] = ((int)(y1f + mh)) * RES + off;
        float nyf = fminf(fmaxf(floorf(__fmul_rn(ysf, syi)), 0.0f), hn - 1.0f);
        ron[k] = ((int)(nyf + mh)) * RES + gnx;
    }

    // ---- issue ALL 28 loads up-front (addresses are always in-bounds) ----
    f32x2 P0[3][4], P1[3][4];
    float M[4];
#pragma unroll
    for (int p = 0; p < 3; ++p) {
        const float* img = rgbs + (size_t)(v * 3 + p) * HW;
#pragma unroll
        for (int k = 0; k < 4; ++k) {
            __builtin_memcpy(&P0[p][k], img + ro0[k], 8);
            __builtin_memcpy(&P1[p][k], img + ro1[k], 8);
        }
    }
    {
        const float* img = masks + (size_t)v * HW;
#pragma unroll
        for (int k = 0; k < 4; ++k) M[k] = img[ron[k]];
    }

    __shared__ float tile[4][32][33];   // [plane][y_local][x_local]
    const float omfx = 1.0f - fx;

#pragma unroll
    for (int p = 0; p < 3; ++p) {
#pragma unroll
        for (int k = 0; k < 4; ++k) {
            float a = ia ? P0[p][k].y : P0[p][k].x;
            float b = ib ? P0[p][k].y : P0[p][k].x;
            float c = ia ? P1[p][k].y : P1[p][k].x;
            float d = ib ? P1[p][k].y : P1[p][k].x;
            float top = a * omfx + b * fx;
            float bot = c * omfx + d * fx;
            float val = top * (1.0f - fy[k]) + bot * fy[k];
            tile[p][ty + 8 * k][tx] = vyk[k] ? val : 0.0f;
        }
    }
#pragma unroll
    for (int k = 0; k < 4; ++k)
        tile[3][ty + 8 * k][tx] = vyk[k] ? M[k] : 0.0f;

    __syncthreads();

    const int xl = 31 - il;   // S x_local for this output row
#pragma unroll
    for (int p = 0; p < 4; ++p) {
        f32x4 w;
        w.x = tile[p][4 * q + 0][xl];
        w.y = tile[p][4 * q + 1][xl];
        w.z = tile[p][4 * q + 2][xl];
        w.w = tile[p][4 * q + 3][xl];
        *(f32x4*)(outp[p] + obase) = w;
    }
}

extern "C" void kernel_launch(void* const* d_in, const int* in_sizes, int n_in,
                              void* d_out, int out_size, void* d_ws, size_t ws_size,
                              hipStream_t stream) {
    const float* rgbs  = (const float*)d_in[0];
    const float* masks = (const float*)d_in[1];
    const float* kc    = (const float*)d_in[2];
    float* out = (float*)d_out;
    int4* part = (int4*)d_ws;                              // NV*128*16 = 16384 B
    float* kc_out = out + (size_t)NV * 3 * HW + (size_t)NV * HW;   // offset 33554432

    bbox_partial<<<dim3(128, NV), 256, 0, stream>>>(masks, part);
    resample_kernel<<<dim3(RES / 32, RES / 32, NV), 256, 0, stream>>>(
        rgbs, masks, part, kc, out, kc_out);
}